// Round 1
// baseline (166.809 us; speedup 1.0000x reference)
//
#include <hip/hip_runtime.h>
#include <hip/hip_bf16.h>

#define LSEQ 4096
#define HDIM 256
#define NS   64
#define PC   32    // number of chunks
#define MC   128   // chunk length (PC*MC == LSEQ)
#define TL   16    // GLU l-tile

// ---------------- LayerNorm stats: one block per token ----------------
__global__ __launch_bounds__(256) void k_ln_stats(const float* __restrict__ x,
                                                  float* __restrict__ mu,
                                                  float* __restrict__ rstd) {
    int l = blockIdx.x, t = threadIdx.x;
    float v = x[l * HDIM + t];
    float s = v, s2 = v * v;
#pragma unroll
    for (int o = 32; o; o >>= 1) {
        s  += __shfl_xor(s, o);
        s2 += __shfl_xor(s2, o);
    }
    __shared__ float ps[4], ps2[4];
    int w = t >> 6;
    if ((t & 63) == 0) { ps[w] = s; ps2[w] = s2; }
    __syncthreads();
    if (t == 0) {
        float S = ps[0] + ps[1] + ps[2] + ps[3];
        float S2 = ps2[0] + ps2[1] + ps2[2] + ps2[3];
        float m = S * (1.0f / HDIM);
        float var = S2 * (1.0f / HDIM) - m * m;
        mu[l] = m;
        rstd[l] = rsqrtf(var + 1e-5f);
    }
}

// ------------- normalize + transpose to xnT[H][L] (coalesced both ways) -------------
__global__ __launch_bounds__(256) void k_transnorm(const float* __restrict__ x,
                                                   const float* __restrict__ mu,
                                                   const float* __restrict__ rstd,
                                                   const float* __restrict__ w,
                                                   const float* __restrict__ b,
                                                   float* __restrict__ xnT) {
    __shared__ float tile[64 * 65];
    int l0 = blockIdx.x * 64, h0 = blockIdx.y * 64;
    int t = threadIdx.x;
#pragma unroll
    for (int i = 0; i < 16; ++i) {
        int e = i * 256 + t;
        int r = e >> 6, c = e & 63;          // r: l-offset, c: h-offset
        int l = l0 + r, h = h0 + c;
        float v = x[l * HDIM + h];
        v = (v - mu[l]) * rstd[l] * w[h] + b[h];
        tile[c * 65 + r] = v;                // store transposed: tile[h][l]
    }
    __syncthreads();
#pragma unroll
    for (int i = 0; i < 16; ++i) {
        int e = i * 256 + t;
        int hh = e >> 6, ll = e & 63;
        xnT[(size_t)(h0 + hh) * LSEQ + l0 + ll] = tile[hh * 65 + ll];
    }
}

// ---------------- shared constant computation ----------------
__device__ inline void ssm_consts(const float* Lre, const float* Lim,
                                  const float* Bre, const float* Bim,
                                  const float* lstep, int h, int n,
                                  float& are, float& aim, float& bre, float& bim) {
    int idx = h * NS + n;
    float lre = Lre[idx], lim = Lim[idx];
    float dt = expf(lstep[h]);
    float er = expf(lre * dt);
    float sa, ca;
    sincosf(lim * dt, &sa, &ca);
    are = er * ca; aim = er * sa;
    // T = (Ab - 1) / Lam
    float inv = 1.0f / (lre * lre + lim * lim);
    float nre = are - 1.0f, nim = aim;
    float tre = (nre * lre + nim * lim) * inv;
    float tim = (nim * lre - nre * lim) * inv;
    float br = Bre[idx], bi = Bim[idx];
    bre = tre * br - tim * bi;
    bim = tre * bi + tim * br;
}

// ---------------- pass 1: chunk-local scan from zero state ----------------
__global__ __launch_bounds__(64) void k_scan_local(const float* __restrict__ xnT,
                                                   const float* __restrict__ Lre,
                                                   const float* __restrict__ Lim,
                                                   const float* __restrict__ Bre,
                                                   const float* __restrict__ Bim,
                                                   const float* __restrict__ lstep,
                                                   float2* __restrict__ f) {
    int c = blockIdx.x, h = blockIdx.y, n = threadIdx.x;
    const float* u = xnT + (size_t)h * LSEQ + c * MC;
    float are, aim, bre, bim;
    ssm_consts(Lre, Lim, Bre, Bim, lstep, h, n, are, aim, bre, bim);
    float sre = 0.f, sim = 0.f;
#pragma unroll 8
    for (int j = 0; j < MC; ++j) {
        float uv = u[j];   // wave-uniform -> scalar load
        float nr = fmaf(are, sre, fmaf(-aim, sim, bre * uv));
        float ni = fmaf(are, sim, fmaf( aim, sre, bim * uv));
        sre = nr; sim = ni;
    }
    f[(size_t)(h * PC + c) * NS + n] = make_float2(sre, sim);
}

// ---------------- pass 2: scan across chunks, emit s0 per chunk + hidden ----------------
__global__ __launch_bounds__(256) void k_scan_chunks(const float* __restrict__ Lre,
                                                     const float* __restrict__ Lim,
                                                     const float* __restrict__ lstep,
                                                     const float2* __restrict__ f,
                                                     float2* __restrict__ s0,
                                                     float* __restrict__ hid,
                                                     int interleaved) {
    int gid = blockIdx.x * 256 + threadIdx.x;   // == h*NS + n
    int h = gid >> 6;
    float lre = Lre[gid], lim = Lim[gid];
    float dt = expf(lstep[h]);
    float er = expf(lre * dt);
    float sa, ca;
    sincosf(lim * dt, &sa, &ca);
    float ar = er * ca, ai = er * sa;
#pragma unroll
    for (int q = 0; q < 7; ++q) {   // Ab^128 by repeated squaring
        float r2 = ar * ar - ai * ai;
        ai = 2.f * ar * ai;
        ar = r2;
    }
    float sre = 0.f, sim = 0.f;
#pragma unroll
    for (int c = 0; c < PC; ++c) {
        size_t idx = (size_t)(h * PC + c) * NS + (gid & 63);
        s0[idx] = make_float2(sre, sim);
        float2 fc = f[idx];
        float nr = fmaf(ar, sre, fmaf(-ai, sim, fc.x));
        float ni = fmaf(ar, sim, fmaf( ai, sre, fc.y));
        sre = nr; sim = ni;
    }
    if (interleaved) {
        ((float2*)hid)[gid] = make_float2(sre, sim);
    } else {
        hid[gid] = sre;
    }
}

// ---------------- pass 3: seeded scan, y reduction, gelu, write gT[H][L] ----------------
__global__ __launch_bounds__(64) void k_scan_out(const float* __restrict__ xnT,
                                                 const float* __restrict__ Lre,
                                                 const float* __restrict__ Lim,
                                                 const float* __restrict__ Bre,
                                                 const float* __restrict__ Bim,
                                                 const float* __restrict__ Cre,
                                                 const float* __restrict__ Cim,
                                                 const float* __restrict__ Dv,
                                                 const float* __restrict__ lstep,
                                                 const float2* __restrict__ s0,
                                                 float* __restrict__ gT) {
    __shared__ float red[64 * 65];
    int c = blockIdx.x, h = blockIdx.y, n = threadIdx.x;
    const float* u = xnT + (size_t)h * LSEQ + c * MC;
    float are, aim, bre, bim;
    ssm_consts(Lre, Lim, Bre, Bim, lstep, h, n, are, aim, bre, bim);
    int idx = h * NS + n;
    float cre = Cre[idx], cim = Cim[idx];
    float Dh = Dv[h];
    float2 s00 = s0[(size_t)(h * PC + c) * NS + n];
    float sre = s00.x, sim = s00.y;

    for (int sub = 0; sub < 2; ++sub) {
#pragma unroll 8
        for (int j = 0; j < 64; ++j) {
            float uv = u[sub * 64 + j];   // wave-uniform -> scalar load
            float nr = fmaf(are, sre, fmaf(-aim, sim, bre * uv));
            float ni = fmaf(are, sim, fmaf( aim, sre, bim * uv));
            sre = nr; sim = ni;
            red[j * 65 + n] = fmaf(cre, sre, -(cim * sim));
        }
        __syncthreads();
        float acc = 0.f;
#pragma unroll
        for (int k = 0; k < 64; ++k) acc += red[n * 65 + k];   // row n == local t
        float uv = u[sub * 64 + n];
        float y = fmaf(2.f, acc, Dh * uv);
        // tanh-approx gelu (jax.nn.gelu default)
        float z = 0.7978845608028654f * fmaf(0.044715f, y * y * y, y);
        float e = __expf(2.f * z);
        float th = 1.f - 2.f / (e + 1.f);
        float g = 0.5f * y * (1.f + th);
        gT[(size_t)h * LSEQ + c * MC + sub * 64 + n] = g;
        __syncthreads();
    }
}

// ---------------- GLU epilogue: out = (g@W1^T+b1)*sigmoid(g@W2^T+b2) + skip ----------------
__global__ __launch_bounds__(256) void k_glu(const float* __restrict__ gT,
                                             const float* __restrict__ W1,
                                             const float* __restrict__ b1v,
                                             const float* __restrict__ W2,
                                             const float* __restrict__ b2v,
                                             const float* __restrict__ x,
                                             float* __restrict__ out) {
    __shared__ float gt[HDIM * TL];   // [k][l], 16 KB
    int l0 = blockIdx.x * TL;
    int t = threadIdx.x;
    {
        float4* dst = (float4*)(gt + t * TL);
        const float4* src = (const float4*)(gT + (size_t)t * LSEQ + l0);
#pragma unroll
        for (int i = 0; i < TL / 4; ++i) dst[i] = src[i];
    }
    __syncthreads();
    float acc1[TL], acc2[TL];
#pragma unroll
    for (int i = 0; i < TL; ++i) { acc1[i] = 0.f; acc2[i] = 0.f; }
    const float* w1r = W1 + t * HDIM;
    const float* w2r = W2 + t * HDIM;
    for (int k = 0; k < HDIM; k += 4) {
        float4 w1 = *(const float4*)(w1r + k);
        float4 w2 = *(const float4*)(w2r + k);
        const float* wa = (const float*)&w1;
        const float* wb = (const float*)&w2;
#pragma unroll
        for (int kk = 0; kk < 4; ++kk) {
            const float4* gk4 = (const float4*)(gt + (k + kk) * TL);
#pragma unroll
            for (int q = 0; q < TL / 4; ++q) {
                float4 gv = gk4[q];
                acc1[4 * q + 0] = fmaf(gv.x, wa[kk], acc1[4 * q + 0]);
                acc1[4 * q + 1] = fmaf(gv.y, wa[kk], acc1[4 * q + 1]);
                acc1[4 * q + 2] = fmaf(gv.z, wa[kk], acc1[4 * q + 2]);
                acc1[4 * q + 3] = fmaf(gv.w, wa[kk], acc1[4 * q + 3]);
                acc2[4 * q + 0] = fmaf(gv.x, wb[kk], acc2[4 * q + 0]);
                acc2[4 * q + 1] = fmaf(gv.y, wb[kk], acc2[4 * q + 1]);
                acc2[4 * q + 2] = fmaf(gv.z, wb[kk], acc2[4 * q + 2]);
                acc2[4 * q + 3] = fmaf(gv.w, wb[kk], acc2[4 * q + 3]);
            }
        }
    }
    float bb1 = b1v[t], bb2 = b2v[t];
#pragma unroll
    for (int i = 0; i < TL; ++i) {
        float a = acc1[i] + bb1;
        float sg = 1.f / (1.f + __expf(-(acc2[i] + bb2)));
        out[(size_t)(l0 + i) * HDIM + t] = fmaf(a, sg, x[(size_t)(l0 + i) * HDIM + t]);
    }
}

extern "C" void kernel_launch(void* const* d_in, const int* in_sizes, int n_in,
                              void* d_out, int out_size, void* d_ws, size_t ws_size,
                              hipStream_t stream) {
    (void)in_sizes; (void)n_in; (void)ws_size;
    const float* x     = (const float*)d_in[0];
    const float* Lre   = (const float*)d_in[1];
    const float* Lim   = (const float*)d_in[2];
    const float* Bre   = (const float*)d_in[3];
    const float* Bim   = (const float*)d_in[4];
    const float* Cre   = (const float*)d_in[5];
    const float* Cim   = (const float*)d_in[6];
    const float* Dv    = (const float*)d_in[7];
    const float* lstep = (const float*)d_in[8];
    const float* lnw   = (const float*)d_in[9];
    const float* lnb   = (const float*)d_in[10];
    const float* W1    = (const float*)d_in[11];
    const float* b1    = (const float*)d_in[12];
    const float* W2    = (const float*)d_in[13];
    const float* b2    = (const float*)d_in[14];

    float* ws   = (float*)d_ws;
    float* mu   = ws;                          // L
    float* rstd = ws + LSEQ;                   // L
    float* xnT  = ws + 2 * LSEQ;               // H*L
    float* gT   = xnT + (size_t)HDIM * LSEQ;   // H*L
    float2* f   = (float2*)(gT + (size_t)HDIM * LSEQ);   // H*PC*NS
    float2* s0  = f + (size_t)HDIM * PC * NS;            // H*PC*NS

    int interleaved = (out_size == LSEQ * HDIM + 2 * HDIM * NS) ? 1 : 0;
    float* hid  = (float*)d_out;
    float* outp = (float*)d_out + (interleaved ? 2 * HDIM * NS : HDIM * NS);

    k_ln_stats  <<<LSEQ, HDIM, 0, stream>>>(x, mu, rstd);
    k_transnorm <<<dim3(LSEQ / 64, HDIM / 64), 256, 0, stream>>>(x, mu, rstd, lnw, lnb, xnT);
    k_scan_local<<<dim3(PC, HDIM), NS, 0, stream>>>(xnT, Lre, Lim, Bre, Bim, lstep, f);
    k_scan_chunks<<<(HDIM * NS) / 256, 256, 0, stream>>>(Lre, Lim, lstep, f, s0, hid, interleaved);
    k_scan_out  <<<dim3(PC, HDIM), NS, 0, stream>>>(xnT, Lre, Lim, Bre, Bim, Cre, Cim, Dv, lstep, s0, gT);
    k_glu       <<<LSEQ / TL, 256, 0, stream>>>(gT, W1, b1, W2, b2, x, outp);
}

// Round 2
// 135.128 us; speedup vs baseline: 1.2345x; 1.2345x over previous
//
#include <hip/hip_runtime.h>
#include <hip/hip_bf16.h>

#define LSEQ 4096
#define HDIM 256
#define NS   64
#define PC   32    // number of chunks
#define MC   128   // chunk length (PC*MC == LSEQ)

typedef __attribute__((ext_vector_type(8))) short short8;
typedef __attribute__((ext_vector_type(4))) float floatx4;

// ---------------- LayerNorm stats: one block per token ----------------
__global__ __launch_bounds__(256) void k_ln_stats(const float* __restrict__ x,
                                                  float* __restrict__ mu,
                                                  float* __restrict__ rstd) {
    int l = blockIdx.x, t = threadIdx.x;
    float v = x[l * HDIM + t];
    float s = v, s2 = v * v;
#pragma unroll
    for (int o = 32; o; o >>= 1) {
        s  += __shfl_xor(s, o);
        s2 += __shfl_xor(s2, o);
    }
    __shared__ float ps[4], ps2[4];
    int w = t >> 6;
    if ((t & 63) == 0) { ps[w] = s; ps2[w] = s2; }
    __syncthreads();
    if (t == 0) {
        float S = ps[0] + ps[1] + ps[2] + ps[3];
        float S2 = ps2[0] + ps2[1] + ps2[2] + ps2[3];
        float m = S * (1.0f / HDIM);
        float var = S2 * (1.0f / HDIM) - m * m;
        mu[l] = m;
        rstd[l] = rsqrtf(var + 1e-5f);
    }
}

// ------------- normalize + transpose to xnT[H][L] (coalesced both ways) -------------
__global__ __launch_bounds__(256) void k_transnorm(const float* __restrict__ x,
                                                   const float* __restrict__ mu,
                                                   const float* __restrict__ rstd,
                                                   const float* __restrict__ w,
                                                   const float* __restrict__ b,
                                                   float* __restrict__ xnT) {
    __shared__ float tile[64 * 65];
    int l0 = blockIdx.x * 64, h0 = blockIdx.y * 64;
    int t = threadIdx.x;
#pragma unroll
    for (int i = 0; i < 16; ++i) {
        int e = i * 256 + t;
        int r = e >> 6, c = e & 63;          // r: l-offset, c: h-offset
        int l = l0 + r, h = h0 + c;
        float v = x[l * HDIM + h];
        v = (v - mu[l]) * rstd[l] * w[h] + b[h];
        tile[c * 65 + r] = v;                // store transposed: tile[h][l]
    }
    __syncthreads();
#pragma unroll
    for (int i = 0; i < 16; ++i) {
        int e = i * 256 + t;
        int hh = e >> 6, ll = e & 63;
        xnT[(size_t)(h0 + hh) * LSEQ + l0 + ll] = tile[hh * 65 + ll];
    }
}

// ---------------- weights -> bf16 prep ----------------
__global__ __launch_bounds__(256) void k_wconv(const float* __restrict__ W1,
                                               const float* __restrict__ W2,
                                               unsigned short* __restrict__ w1b,
                                               unsigned short* __restrict__ w2b) {
    int g = blockIdx.x * 256 + threadIdx.x;      // 16384 threads, 4 elems each
    float4 a = ((const float4*)W1)[g];
    float4 c = ((const float4*)W2)[g];
    ushort4 o1, o2;
    __hip_bfloat16 h;
    h = __float2bfloat16(a.x); o1.x = *(unsigned short*)&h;
    h = __float2bfloat16(a.y); o1.y = *(unsigned short*)&h;
    h = __float2bfloat16(a.z); o1.z = *(unsigned short*)&h;
    h = __float2bfloat16(a.w); o1.w = *(unsigned short*)&h;
    h = __float2bfloat16(c.x); o2.x = *(unsigned short*)&h;
    h = __float2bfloat16(c.y); o2.y = *(unsigned short*)&h;
    h = __float2bfloat16(c.z); o2.z = *(unsigned short*)&h;
    h = __float2bfloat16(c.w); o2.w = *(unsigned short*)&h;
    ((ushort4*)w1b)[g] = o1;
    ((ushort4*)w2b)[g] = o2;
}

// ---------------- shared constant computation ----------------
__device__ inline void ssm_consts(const float* Lre, const float* Lim,
                                  const float* Bre, const float* Bim,
                                  const float* lstep, int h, int n,
                                  float& are, float& aim, float& bre, float& bim) {
    int idx = h * NS + n;
    float lre = Lre[idx], lim = Lim[idx];
    float dt = expf(lstep[h]);
    float er = expf(lre * dt);
    float sa, ca;
    sincosf(lim * dt, &sa, &ca);
    are = er * ca; aim = er * sa;
    // T = (Ab - 1) / Lam
    float inv = 1.0f / (lre * lre + lim * lim);
    float nre = are - 1.0f, nim = aim;
    float tre = (nre * lre + nim * lim) * inv;
    float tim = (nim * lre - nre * lim) * inv;
    float br = Bre[idx], bi = Bim[idx];
    bre = tre * br - tim * bi;
    bim = tre * bi + tim * br;
}

// ---------------- pass 1: chunk-local scan from zero state ----------------
// 4 waves/block, one chunk per wave.
__global__ __launch_bounds__(256) void k_scan_local(const float* __restrict__ xnT,
                                                    const float* __restrict__ Lre,
                                                    const float* __restrict__ Lim,
                                                    const float* __restrict__ Bre,
                                                    const float* __restrict__ Bim,
                                                    const float* __restrict__ lstep,
                                                    float2* __restrict__ f) {
    int wv = __builtin_amdgcn_readfirstlane((int)threadIdx.x) >> 6;  // uniform wave id
    int n = threadIdx.x & 63;
    int c = blockIdx.x * 4 + wv, h = blockIdx.y;
    const float* u = xnT + (size_t)h * LSEQ + c * MC;   // wave-uniform base
    float are, aim, bre, bim;
    ssm_consts(Lre, Lim, Bre, Bim, lstep, h, n, are, aim, bre, bim);
    float sre = 0.f, sim = 0.f;
#pragma unroll 8
    for (int j = 0; j < MC; ++j) {
        float uv = u[j];   // uniform -> s_load
        float nr = fmaf(are, sre, fmaf(-aim, sim, bre * uv));
        float ni = fmaf(are, sim, fmaf( aim, sre, bim * uv));
        sre = nr; sim = ni;
    }
    f[(size_t)(h * PC + c) * NS + n] = make_float2(sre, sim);
}

// ---------------- pass 2: scan across chunks, emit s0 per chunk + hidden ----------------
__global__ __launch_bounds__(256) void k_scan_chunks(const float* __restrict__ Lre,
                                                     const float* __restrict__ Lim,
                                                     const float* __restrict__ lstep,
                                                     const float2* __restrict__ f,
                                                     float2* __restrict__ s0,
                                                     float* __restrict__ hid,
                                                     int interleaved) {
    int gid = blockIdx.x * 256 + threadIdx.x;   // == h*NS + n
    int h = gid >> 6;
    float lre = Lre[gid], lim = Lim[gid];
    float dt = expf(lstep[h]);
    float er = expf(lre * dt);
    float sa, ca;
    sincosf(lim * dt, &sa, &ca);
    float ar = er * ca, ai = er * sa;
#pragma unroll
    for (int q = 0; q < 7; ++q) {   // Ab^128 by repeated squaring
        float r2 = ar * ar - ai * ai;
        ai = 2.f * ar * ai;
        ar = r2;
    }
    float sre = 0.f, sim = 0.f;
#pragma unroll
    for (int c = 0; c < PC; ++c) {
        size_t idx = (size_t)(h * PC + c) * NS + (gid & 63);
        s0[idx] = make_float2(sre, sim);
        float2 fc = f[idx];
        float nr = fmaf(ar, sre, fmaf(-ai, sim, fc.x));
        float ni = fmaf(ar, sim, fmaf( ai, sre, fc.y));
        sre = nr; sim = ni;
    }
    if (interleaved) {
        ((float2*)hid)[gid] = make_float2(sre, sim);
    } else {
        hid[gid] = sre;
    }
}

// ---------------- pass 3: seeded scan, 16-token-group reduction, gelu, g bf16 [L][H] ----
// 4 waves/block, one chunk per wave. LDS: 4 x 16x68 floats = 17.4 KB/block.
__global__ __launch_bounds__(256) void k_scan_out(const float* __restrict__ xnT,
                                                  const float* __restrict__ Lre,
                                                  const float* __restrict__ Lim,
                                                  const float* __restrict__ Bre,
                                                  const float* __restrict__ Bim,
                                                  const float* __restrict__ Cre,
                                                  const float* __restrict__ Cim,
                                                  const float* __restrict__ Dv,
                                                  const float* __restrict__ lstep,
                                                  const float2* __restrict__ s0,
                                                  __hip_bfloat16* __restrict__ gb) {
    __shared__ __align__(16) float red[4][16 * 68];
    int wv = __builtin_amdgcn_readfirstlane((int)threadIdx.x) >> 6;  // uniform wave id
    int lane = threadIdx.x & 63;
    int c = blockIdx.x * 4 + wv, h = blockIdx.y, n = lane;
    const float* u = xnT + (size_t)h * LSEQ + c * MC;   // wave-uniform base
    float are, aim, bre, bim;
    ssm_consts(Lre, Lim, Bre, Bim, lstep, h, n, are, aim, bre, bim);
    int idx = h * NS + n;
    float cre = Cre[idx], cim = Cim[idx];
    float Dh = Dv[h];
    float2 s00 = s0[(size_t)(h * PC + c) * NS + n];
    float sre = s00.x, sim = s00.y;

    float* rw = red[wv];
    int t16 = lane & 15, p = lane >> 4;

    for (int jg = 0; jg < 8; ++jg) {            // 8 groups of 16 tokens
#pragma unroll
        for (int tt = 0; tt < 16; ++tt) {
            float uv = u[jg * 16 + tt];          // uniform -> s_load
            float nr = fmaf(are, sre, fmaf(-aim, sim, bre * uv));
            float ni = fmaf(are, sim, fmaf( aim, sre, bim * uv));
            sre = nr; sim = ni;
            rw[tt * 68 + n] = fmaf(cre, sre, -(cim * sim));
        }
        // lane (t16,p) sums n in [16p,16p+16) for token t16, then combine over p
        float a0 = 0.f;
        const float4* rp = (const float4*)(rw + t16 * 68 + p * 16);
#pragma unroll
        for (int qq = 0; qq < 4; ++qq) {
            float4 v = rp[qq];
            a0 += (v.x + v.y) + (v.z + v.w);
        }
        a0 += __shfl_xor(a0, 16);
        a0 += __shfl_xor(a0, 32);
        if (lane < 16) {
            int l = c * MC + jg * 16 + t16;
            float uv2 = u[jg * 16 + t16];
            float y = fmaf(2.f, a0, Dh * uv2);
            // tanh-approx gelu (jax.nn.gelu default)
            float z = 0.7978845608028654f * fmaf(0.044715f, y * y * y, y);
            float e = __expf(2.f * z);
            float th = 1.f - 2.f / (e + 1.f);
            float g = 0.5f * y * (1.f + th);
            gb[(size_t)l * HDIM + h] = __float2bfloat16(g);
        }
    }
}

// ---------------- GLU epilogue via MFMA, LDS-free ----------------
// One wave per block computes a 32(l) x 32(h) out tile for BOTH GEMMs.
// A = g [L][K=256] bf16 row-major; B^T = W [h][k] row-major bf16.
__global__ __launch_bounds__(64) void k_glu_mfma(const unsigned short* __restrict__ gbs,
                                                 const unsigned short* __restrict__ w1b,
                                                 const unsigned short* __restrict__ w2b,
                                                 const float* __restrict__ b1v,
                                                 const float* __restrict__ b2v,
                                                 const float* __restrict__ x,
                                                 float* __restrict__ out) {
    int bx = blockIdx.x;
    int m0 = (bx >> 3) * 32;        // 128 m-tiles
    int n0 = (bx & 7) * 32;         // 8 n-tiles
    int lane = threadIdx.x;
    int t = lane & 15, q = lane >> 4;

    floatx4 acc[2][2][2];           // [mt][nt][{W1,W2}]
#pragma unroll
    for (int a = 0; a < 2; ++a)
#pragma unroll
        for (int b = 0; b < 2; ++b)
#pragma unroll
            for (int g = 0; g < 2; ++g)
                acc[a][b][g] = (floatx4){0.f, 0.f, 0.f, 0.f};

    const unsigned short* A0  = gbs + (size_t)(m0 + t) * HDIM + q * 8;
    const unsigned short* A1  = A0 + 16 * HDIM;
    const unsigned short* B10 = w1b + (size_t)(n0 + t) * HDIM + q * 8;
    const unsigned short* B11 = B10 + 16 * HDIM;
    const unsigned short* B20 = w2b + (size_t)(n0 + t) * HDIM + q * 8;
    const unsigned short* B21 = B20 + 16 * HDIM;

#pragma unroll
    for (int ks = 0; ks < 8; ++ks) {
        int off = ks * 32;
        short8 a0  = *(const short8*)(A0  + off);
        short8 a1  = *(const short8*)(A1  + off);
        short8 b10 = *(const short8*)(B10 + off);
        short8 b11 = *(const short8*)(B11 + off);
        short8 b20 = *(const short8*)(B20 + off);
        short8 b21 = *(const short8*)(B21 + off);
        acc[0][0][0] = __builtin_amdgcn_mfma_f32_16x16x32_bf16(a0, b10, acc[0][0][0], 0, 0, 0);
        acc[0][1][0] = __builtin_amdgcn_mfma_f32_16x16x32_bf16(a0, b11, acc[0][1][0], 0, 0, 0);
        acc[1][0][0] = __builtin_amdgcn_mfma_f32_16x16x32_bf16(a1, b10, acc[1][0][0], 0, 0, 0);
        acc[1][1][0] = __builtin_amdgcn_mfma_f32_16x16x32_bf16(a1, b11, acc[1][1][0], 0, 0, 0);
        acc[0][0][1] = __builtin_amdgcn_mfma_f32_16x16x32_bf16(a0, b20, acc[0][0][1], 0, 0, 0);
        acc[0][1][1] = __builtin_amdgcn_mfma_f32_16x16x32_bf16(a0, b21, acc[0][1][1], 0, 0, 0);
        acc[1][0][1] = __builtin_amdgcn_mfma_f32_16x16x32_bf16(a1, b20, acc[1][0][1], 0, 0, 0);
        acc[1][1][1] = __builtin_amdgcn_mfma_f32_16x16x32_bf16(a1, b21, acc[1][1][1], 0, 0, 0);
    }

#pragma unroll
    for (int nt = 0; nt < 2; ++nt) {
        int hh = n0 + nt * 16 + t;
        float bb1 = b1v[hh], bb2 = b2v[hh];
#pragma unroll
        for (int mt = 0; mt < 2; ++mt) {
#pragma unroll
            for (int reg = 0; reg < 4; ++reg) {
                int l = m0 + mt * 16 + q * 4 + reg;   // C/D: row=(lane>>4)*4+reg, col=lane&15
                float a  = acc[mt][nt][0][reg] + bb1;
                float sg = 1.f / (1.f + __expf(-(acc[mt][nt][1][reg] + bb2)));
                out[(size_t)l * HDIM + hh] = fmaf(a, sg, x[(size_t)l * HDIM + hh]);
            }
        }
    }
}

extern "C" void kernel_launch(void* const* d_in, const int* in_sizes, int n_in,
                              void* d_out, int out_size, void* d_ws, size_t ws_size,
                              hipStream_t stream) {
    (void)in_sizes; (void)n_in; (void)ws_size;
    const float* x     = (const float*)d_in[0];
    const float* Lre   = (const float*)d_in[1];
    const float* Lim   = (const float*)d_in[2];
    const float* Bre   = (const float*)d_in[3];
    const float* Bim   = (const float*)d_in[4];
    const float* Cre   = (const float*)d_in[5];
    const float* Cim   = (const float*)d_in[6];
    const float* Dv    = (const float*)d_in[7];
    const float* lstep = (const float*)d_in[8];
    const float* lnw   = (const float*)d_in[9];
    const float* lnb   = (const float*)d_in[10];
    const float* W1    = (const float*)d_in[11];
    const float* b1    = (const float*)d_in[12];
    const float* W2    = (const float*)d_in[13];
    const float* b2    = (const float*)d_in[14];

    float* ws   = (float*)d_ws;
    float* mu   = ws;                          // L
    float* rstd = ws + LSEQ;                   // L
    float* xnT  = ws + 2 * LSEQ;               // H*L
    float2* f   = (float2*)(xnT + (size_t)HDIM * LSEQ);  // H*PC*NS float2
    float2* s0  = f + (size_t)HDIM * PC * NS;            // H*PC*NS float2
    unsigned short* gb  = (unsigned short*)(s0 + (size_t)HDIM * PC * NS);  // L*H bf16
    unsigned short* w1b = gb + (size_t)LSEQ * HDIM;      // H*H bf16
    unsigned short* w2b = w1b + HDIM * HDIM;             // H*H bf16

    int interleaved = (out_size == LSEQ * HDIM + 2 * HDIM * NS) ? 1 : 0;
    float* hid  = (float*)d_out;
    float* outp = (float*)d_out + (interleaved ? 2 * HDIM * NS : HDIM * NS);

    k_ln_stats   <<<LSEQ, 256, 0, stream>>>(x, mu, rstd);
    k_transnorm  <<<dim3(LSEQ / 64, HDIM / 64), 256, 0, stream>>>(x, mu, rstd, lnw, lnb, xnT);
    k_wconv      <<<64, 256, 0, stream>>>(W1, W2, w1b, w2b);
    k_scan_local <<<dim3(PC / 4, HDIM), 256, 0, stream>>>(xnT, Lre, Lim, Bre, Bim, lstep, f);
    k_scan_chunks<<<(HDIM * NS) / 256, 256, 0, stream>>>(Lre, Lim, lstep, f, s0, hid, interleaved);
    k_scan_out   <<<dim3(PC / 4, HDIM), 256, 0, stream>>>(xnT, Lre, Lim, Bre, Bim, Cre, Cim,
                                                          Dv, lstep, s0, (__hip_bfloat16*)gb);
    k_glu_mfma   <<<128 * 8, 64, 0, stream>>>(gb, w1b, w2b, b1, b2, x, outp);
}